// Round 8
// baseline (2830.945 us; speedup 1.0000x reference)
//
#include <hip/hip_runtime.h>
#include <hip/hip_bf16.h>

typedef __hip_bfloat16 bf16;
typedef __attribute__((ext_vector_type(8))) short bf16x8;
typedef __attribute__((ext_vector_type(4))) float f32x4;

#define HH 300     // hidden
#define NMOLS 2000
#define AFD 133    // atom feature dim
#define BFD 147    // bond feature dim
#define KP 480     // padded K of WT buffers (15 steps of 32)
#define GOFS 160   // tail region starts at k=160 (step 5)
#define NWT (320 * KP)   // elements per WT buffer
#define NT 19      // 19 col tiles of 16 = 304 (>=300)

// ---- build WT[c][k] bf16: k<fd -> W0[k][c]; 160<=k<460 -> W1[k-160][c]; else 0 ----
// Zero pads are load-bearing: A-tail reads run past k=460 (MODE2: 444) and rows
// past 300 elems; those products hit WT==0.
__global__ void build_wt(const float* __restrict__ W0, const float* __restrict__ W1,
                         int fd, bf16* __restrict__ WT)
{
  int idx = blockIdx.x * 256 + threadIdx.x;
  if (idx >= NWT) return;
  int c = idx / KP, k = idx - c * KP;
  float v = 0.f;
  if (c < HH) {
    if (k < fd) v = W0[(size_t)k * HH + c];
    else if (k >= GOFS && k < GOFS + HH) v = W1[(size_t)(k - GOFS) * HH + c];
  }
  WT[idx] = __float2bfloat16(v);
}

// ---- amsg[a][k] = sum_j msg[a2b[a][j]][k], bf16; thread = 4 elems (8B loads) ----
__global__ __launch_bounds__(256)
void gather6_k(const bf16* __restrict__ msg, const int* __restrict__ a2b,
               bf16* __restrict__ amsg, int A)
{
  int idx = blockIdx.x * 256 + threadIdx.x;
  if (idx >= A * 75) return;
  int a = idx / 75;
  int k4 = (idx - a * 75) * 4;
  const int* p = a2b + (size_t)a * 6;
  float s[4] = {0.f, 0.f, 0.f, 0.f};
#pragma unroll
  for (int j = 0; j < 6; j++) {
    uint2 u = *(const uint2*)(msg + (size_t)p[j] * HH + k4);
    union { unsigned u; float f; } c;
    c.u = u.x << 16;         s[0] += c.f;
    c.u = u.x & 0xffff0000u; s[1] += c.f;
    c.u = u.y << 16;         s[2] += c.f;
    c.u = u.y & 0xffff0000u; s[3] += c.f;
  }
  bf16 t[4];
#pragma unroll
  for (int j = 0; j < 4; j++) t[j] = __float2bfloat16(s[j]);
  *(uint2*)(amsg + (size_t)a * HH + k4) = *(const uint2*)t;
}

__device__ inline bf16x8 mk8(uint2 u0, uint2 u1) {
  union { struct { uint2 a, b; } p; bf16x8 v; } c;
  c.p.a = u0; c.p.b = u1;
  return c.v;
}
// bf16x8 = bf16(a - b) elementwise, from packed uint2 pairs
__device__ inline bf16x8 sub8(uint2 a0, uint2 a1, uint2 b0, uint2 b1) {
  unsigned wa[4] = {a0.x, a0.y, a1.x, a1.y};
  unsigned wb[4] = {b0.x, b0.y, b1.x, b1.y};
  bf16x8 t;
#pragma unroll
  for (int q = 0; q < 4; q++) {
    union { unsigned u; float f; } alo, ahi, blo, bhi;
    alo.u = wa[q] << 16;         blo.u = wb[q] << 16;
    ahi.u = wa[q] & 0xffff0000u; bhi.u = wb[q] & 0xffff0000u;
    union { bf16 b; short s; } c0, c1;
    c0.b = __float2bfloat16(alo.f - blo.f);
    c1.b = __float2bfloat16(ahi.f - bhi.f);
    t[2 * q] = c0.s; t[2 * q + 1] = c1.s;
  }
  return t;
}

// ============ barrier-free, LDS-free MFMA GEMM: each wave owns 32 rows x 300 cols ======
// A-frag of mfma_16x16x32 is lane(r=lane&15, q=lane>>4) -> A[row r][k q*8..+8]:
// loaded straight from global (4 q-lanes = one 64B row chunk, full-line).
// K layout: steps 0..4 = features (A0 f32, k<FD), steps 5..14 = tail:
//   MODE 0: (5 steps only)                      msg_out = relu(C), row0=0
//   MODE 1: tail = amsg[b2a[r]] - msg[b2revb[r]] (fused, in-register)
//   MODE 2: tail = amsg[r];                     hid = relu(C + bias)
template<int MODE>
__global__ __launch_bounds__(256, 2)
void gemm_w(const float* __restrict__ A0, const bf16* __restrict__ WT,
            const int* __restrict__ b2a, const int* __restrict__ b2revb,
            const bf16* __restrict__ amsg, const bf16* __restrict__ msgc,
            const float* __restrict__ bias,
            bf16* __restrict__ msg_out, float* __restrict__ hid_out, int M)
{
  constexpr int KSTEPS = (MODE == 0) ? 5 : 15;
  constexpr int FD = (MODE == 2) ? AFD : BFD;

  const int lane = (int)(threadIdx.x & 63);
  const int wave = (int)(threadIdx.x >> 6);
  const int w0 = (blockIdx.x * 4 + wave) * 32;   // this wave's first row
  const int r = lane & 15;
  const int q = lane >> 4;

  const int cr0 = min(w0 + r, M - 1);        // clamped rows (stores guarded)
  const int cr1 = min(w0 + 16 + r, M - 1);

  int ba0 = 0, rb0 = 0, ba1 = 0, rb1 = 0;
  if (MODE == 1) {
    ba0 = b2a[cr0]; rb0 = b2revb[cr0];
    ba1 = b2a[cr1]; rb1 = b2revb[cr1];
  }

  f32x4 acc[2][NT];
#pragma unroll
  for (int f = 0; f < 2; f++)
#pragma unroll
    for (int j = 0; j < NT; j++) acc[f][j] = (f32x4){0.f, 0.f, 0.f, 0.f};

  const bf16* bb = WT + (size_t)r * KP + q * 8;  // + j*16*KP + s*32

#pragma unroll
  for (int s = 0; s < KSTEPS; s++) {
    bf16x8 a0f, a1f;
    if (s < 5) {
      const int kb = s * 32 + q * 8;
      float v0[8], v1[8];
#pragma unroll
      for (int j = 0; j < 8; j++) {
        int k = kb + j;
        v0[j] = (k < FD) ? A0[(size_t)cr0 * FD + k] : 0.f;
        v1[j] = (k < FD) ? A0[(size_t)cr1 * FD + k] : 0.f;
      }
#pragma unroll
      for (int j = 0; j < 8; j++) {
        union { bf16 b; short sh; } c0, c1;
        c0.b = __float2bfloat16(v0[j]); c1.b = __float2bfloat16(v1[j]);
        a0f[j] = c0.sh; a1f[j] = c1.sh;
      }
    } else {
      const int kk = (s - 5) * 32 + q * 8;
      if (MODE == 1) {
        const char* pa0 = (const char*)(amsg + (size_t)ba0 * HH + kk);
        const char* pb0 = (const char*)(msgc + (size_t)rb0 * HH + kk);
        const char* pa1 = (const char*)(amsg + (size_t)ba1 * HH + kk);
        const char* pb1 = (const char*)(msgc + (size_t)rb1 * HH + kk);
        uint2 A00 = *(const uint2*)pa0, A01 = *(const uint2*)(pa0 + 8);
        uint2 B00 = *(const uint2*)pb0, B01 = *(const uint2*)(pb0 + 8);
        uint2 A10 = *(const uint2*)pa1, A11 = *(const uint2*)(pa1 + 8);
        uint2 B10 = *(const uint2*)pb1, B11 = *(const uint2*)(pb1 + 8);
        a0f = sub8(A00, A01, B00, B01);
        a1f = sub8(A10, A11, B10, B11);
      } else {  // MODE 2: dense amsg rows
        const char* pa0 = (const char*)(amsg + (size_t)cr0 * HH + kk);
        const char* pa1 = (const char*)(amsg + (size_t)cr1 * HH + kk);
        a0f = mk8(*(const uint2*)pa0, *(const uint2*)(pa0 + 8));
        a1f = mk8(*(const uint2*)pa1, *(const uint2*)(pa1 + 8));
      }
    }
#pragma unroll
    for (int j = 0; j < NT; j++) {
      bf16x8 bfr = *(const bf16x8*)(bb + (size_t)j * 16 * KP + s * 32);
      acc[0][j] = __builtin_amdgcn_mfma_f32_16x16x32_bf16(a0f, bfr, acc[0][j], 0, 0, 0);
      acc[1][j] = __builtin_amdgcn_mfma_f32_16x16x32_bf16(a1f, bfr, acc[1][j], 0, 0, 0);
    }
  }

  // ---- epilogue: C/D frag col=lane&15, row=(lane>>4)*4+reg ----
#pragma unroll
  for (int j = 0; j < NT; j++) {
    int c = j * 16 + r;
    if (c >= HH) continue;   // only j=18, r>=12
    float bia = (MODE == 2) ? bias[c] : 0.f;
#pragma unroll
    for (int f = 0; f < 2; f++) {
#pragma unroll
      for (int ri = 0; ri < 4; ri++) {
        int g = w0 + f * 16 + q * 4 + ri;
        if (g >= M) continue;
        float v = acc[f][j][ri];
        if (MODE == 2) {
          hid_out[(size_t)g * HH + c] = fmaxf(v + bia, 0.f);
        } else {
          float rv = fmaxf(v, 0.f);
          if (g == 0) rv = 0.f;
          msg_out[(size_t)g * HH + c] = __float2bfloat16(rv);
        }
      }
    }
  }
}

// per-molecule mean over sorted mol_id (binary search, no atomics)
__global__ void readout_k(const float* __restrict__ hid, const int* __restrict__ mol_id,
                          float* __restrict__ out, int A)
{
  __shared__ int bnd[2];
  int m = blockIdx.x;
  if (threadIdx.x < 2) {
    int target = m + (int)threadIdx.x;
    int lo = 0, hi = A;
    while (lo < hi) { int mid = (lo + hi) >> 1; if (mol_id[mid] < target) lo = mid + 1; else hi = mid; }
    bnd[threadIdx.x] = lo;
  }
  __syncthreads();
  int s = bnd[0], e = bnd[1];
  int h = threadIdx.x;
  if (h >= HH) return;
  float acc = 0.f;
  for (int a = s; a < e; a++) acc += hid[(size_t)a * HH + h];
  int cnt = e - s; if (cnt < 1) cnt = 1;
  out[(size_t)m * HH + h] = acc / (float)cnt;
}

extern "C" void kernel_launch(void* const* d_in, const int* in_sizes, int n_in,
                              void* d_out, int out_size, void* d_ws, size_t ws_size,
                              hipStream_t stream)
{
  const float* f_atoms[2] = {(const float*)d_in[0], (const float*)d_in[2]};
  const float* f_bonds[2] = {(const float*)d_in[1], (const float*)d_in[3]};
  const float* W_i[2]     = {(const float*)d_in[4], (const float*)d_in[5]};
  const float* W_h[2]     = {(const float*)d_in[6], (const float*)d_in[7]};
  const float* W_o[2]     = {(const float*)d_in[8], (const float*)d_in[10]};
  const float* b_o[2]     = {(const float*)d_in[9], (const float*)d_in[11]};
  const int* a2b[2]    = {(const int*)d_in[12], (const int*)d_in[16]};
  const int* b2a[2]    = {(const int*)d_in[13], (const int*)d_in[17]};
  const int* b2revb[2] = {(const int*)d_in[14], (const int*)d_in[18]};
  const int* mol_id[2] = {(const int*)d_in[15], (const int*)d_in[19]};
  const int A = in_sizes[0] / AFD;   // 100001
  const int B = in_sizes[1] / BFD;   // 200001

  // ws: M0 bf16[B,H] | M1 bf16[B,H] / hid f32[A,H] overlay | amsg bf16[A,H] | 4x WT
  auto al = [](size_t x){ return (x + 255) & ~(size_t)255; };
  size_t r0 = al((size_t)B * HH * sizeof(bf16));
  size_t r1sz = (size_t)B * HH * sizeof(bf16);
  size_t hsz  = (size_t)A * HH * sizeof(float);
  size_t r1 = al(r1sz > hsz ? r1sz : hsz);
  size_t amsz = al((size_t)A * HH * sizeof(bf16));
  size_t wtsz = al((size_t)NWT * sizeof(bf16));
  if (ws_size < r0 + r1 + amsz + 4 * wtsz) return;  // proven available (round 5)

  char* ws = (char*)d_ws;
  bf16*  M0  = (bf16*)ws;
  bf16*  M1  = (bf16*)(ws + r0);
  float* hid = (float*)(ws + r0);
  bf16*  amsg = (bf16*)(ws + r0 + r1);
  size_t wofs = r0 + r1 + amsz;
  bf16* WT1[2] = {(bf16*)(ws + wofs),            (bf16*)(ws + wofs + wtsz)};
  bf16* WT2[2] = {(bf16*)(ws + wofs + 2 * wtsz), (bf16*)(ws + wofs + 3 * wtsz)};

  dim3 blk(256);
  dim3 gW((NWT + 255) / 256);
  dim3 gB((B + 127) / 128);    // 128 rows/block (4 waves x 32)
  dim3 gA((A + 127) / 128);
  dim3 gG((A * 75 + 255) / 256);

  for (int p = 0; p < 2; p++) {
    build_wt<<<gW, blk, 0, stream>>>(W_i[p], W_h[p], BFD, WT1[p]);
    build_wt<<<gW, blk, 0, stream>>>(W_o[p], W_o[p] + (size_t)AFD * HH, AFD, WT2[p]);
  }

  for (int p = 0; p < 2; p++) {
    float* out_p = (float*)d_out + (size_t)p * NMOLS * HH;
    // msg(M0) = relu(f_bonds @ W_i), row0=0
    gemm_w<0><<<gB, blk, 0, stream>>>(f_bonds[p], WT1[p], nullptr, nullptr,
                                      nullptr, nullptr, nullptr, M0, nullptr, B);
    // iteration 1: amsg = gather6(M0); M1 = relu(fb@Wi + (amsg[b2a]-M0[b2revb])@Wh)
    gather6_k<<<gG, blk, 0, stream>>>(M0, a2b[p], amsg, A);
    gemm_w<1><<<gB, blk, 0, stream>>>(f_bonds[p], WT1[p], b2a[p], b2revb[p],
                                      amsg, M0, nullptr, M1, nullptr, B);
    // iteration 2
    gather6_k<<<gG, blk, 0, stream>>>(M1, a2b[p], amsg, A);
    gemm_w<1><<<gB, blk, 0, stream>>>(f_bonds[p], WT1[p], b2a[p], b2revb[p],
                                      amsg, M1, nullptr, M0, nullptr, B);
    // output layer
    gather6_k<<<gG, blk, 0, stream>>>(M0, a2b[p], amsg, A);
    gemm_w<2><<<gA, blk, 0, stream>>>(f_atoms[p], WT2[p], nullptr, nullptr,
                                      amsg, nullptr, b_o[p], nullptr, hid, A);
    // per-molecule mean readout
    readout_k<<<NMOLS, 320, 0, stream>>>(hid, mol_id[p], out_p, A);
  }
}

// Round 9
// 2459.470 us; speedup vs baseline: 1.1510x; 1.1510x over previous
//
#include <hip/hip_runtime.h>
#include <hip/hip_bf16.h>

typedef __hip_bfloat16 bf16;
typedef __attribute__((ext_vector_type(8))) short bf16x8;
typedef __attribute__((ext_vector_type(4))) float f32x4;

#define HH 300     // hidden
#define NMOLS 2000
#define AFD 133    // atom feature dim
#define BFD 147    // bond feature dim

// ---- generic weight-transpose builder: WT[c][k], c<320, k<kp ----
// k<fd -> W0[k][c]; gofs<=k<gofs+300 -> W1[k-gofs][c]; else 0 (pads load-bearing)
__global__ void build_wt(const float* __restrict__ W0, const float* __restrict__ W1,
                         int fd, int gofs, int kp, bf16* __restrict__ WT)
{
  int idx = blockIdx.x * 256 + threadIdx.x;
  if (idx >= 320 * kp) return;
  int c = idx / kp, k = idx - c * kp;
  float v = 0.f;
  if (c < HH) {
    if (k < fd) v = W0[(size_t)k * HH + c];
    else if (gofs >= 0 && k >= gofs && k < gofs + HH) v = W1[(size_t)(k - gofs) * HH + c];
  }
  WT[idx] = __float2bfloat16(v);
}

// ---- amsg[a][k] = sum_j msg[a2b[a][j]][k], bf16; thread = 4 elems (8B loads) ----
__global__ __launch_bounds__(256)
void gather6_k(const bf16* __restrict__ msg, const int* __restrict__ a2b,
               bf16* __restrict__ amsg, int A)
{
  int idx = blockIdx.x * 256 + threadIdx.x;
  if (idx >= A * 75) return;
  int a = idx / 75;
  int k4 = (idx - a * 75) * 4;
  const int* p = a2b + (size_t)a * 6;
  float s[4] = {0.f, 0.f, 0.f, 0.f};
#pragma unroll
  for (int j = 0; j < 6; j++) {
    uint2 u = *(const uint2*)(msg + (size_t)p[j] * HH + k4);
    union { unsigned u; float f; } c;
    c.u = u.x << 16;         s[0] += c.f;
    c.u = u.x & 0xffff0000u; s[1] += c.f;
    c.u = u.y << 16;         s[2] += c.f;
    c.u = u.y & 0xffff0000u; s[3] += c.f;
  }
  bf16 t[4];
#pragma unroll
  for (int j = 0; j < 4; j++) t[j] = __float2bfloat16(s[j]);
  *(uint2*)(amsg + (size_t)a * HH + k4) = *(const uint2*)t;
}

// ============ pipelined MFMA GEMM: 32 rows x 320 cols per block, 4 waves split N ========
// wave = 32 rows x 80 cols, acc[2][5] (40 AGPR) -> ~3 waves/EU occupancy.
// MODE 0: C = f_bonds@Wi (5 steps, KP=160);  write inp(bf16, if ptr) + msg=relu(C),row0=0
// MODE 1: C = t@Wh (10 steps, KP=320), t = amsg[b2a[r]]-msg[b2revb[r]] fused;
//         out = relu(inp + C), row0=0
// MODE 2: C = [f_atoms|amsg]@Wo (15 steps, KP=480, tail@step5);  hid = relu(C + bias)
// MODE 3: C = f_bonds@Wi + t@Wh (15 steps, KP=480);  out = relu(C), row0=0  [fallback]
template<int MODE>
__global__ __launch_bounds__(256, 3)
void gemm32(const float* __restrict__ A0, const bf16* __restrict__ WT,
            const int* __restrict__ b2a, const int* __restrict__ b2revb,
            const bf16* __restrict__ amsg, const bf16* __restrict__ msgc,
            const bf16* __restrict__ inp, const float* __restrict__ bias,
            bf16* __restrict__ inp_out, bf16* __restrict__ msg_out,
            float* __restrict__ hid_out, int M)
{
  constexpr int KSTEPS = (MODE == 0) ? 5 : (MODE == 1) ? 10 : 15;
  constexpr int KP     = (MODE == 0) ? 160 : (MODE == 1) ? 320 : 480;
  constexpr int TAIL0  = (MODE == 1) ? 0 : 5;   // first tail step
  constexpr int FD     = (MODE == 2) ? AFD : BFD;

  __shared__ __align__(16) short As[4][32 * 32];   // 4-deep ring, 2KB each

  const int tid = threadIdx.x;
  const int lane = tid & 63;
  const int wave = tid >> 6;           // col group 0..3
  const int gm0 = blockIdx.x * 32;
  const int r = lane & 15, q = lane >> 4;

  // staging role: 8 threads per row, 4 bf16 (8B) per thread per step
  const int sr = tid >> 3;             // row 0..31
  const int ss = tid & 7;              // 8B slot
  const int arow = gm0 + sr;
  const bool rok = arow < M;
  const int crow = rok ? arow : 0;
  // 16B-pair XOR swizzle (pair p = ss>>1 swizzled by row>>1; w = ss&1 inside pair)
  const int stoff = sr * 32 + (((ss >> 1) ^ (sr >> 1)) & 3) * 8 + (ss & 1) * 4;

  int ba = 0, rb = 0;
  if (MODE == 1 || MODE == 3) { ba = b2a[crow]; rb = b2revb[crow]; }

  // compute role: A-frag LDS offsets (2 row tiles), B global base
  int aoff[2];
#pragma unroll
  for (int f = 0; f < 2; f++) {
    int rr = f * 16 + r;
    aoff[f] = rr * 32 + ((q ^ (rr >> 1)) & 3) * 8;
  }
  const bf16* bb = WT + (size_t)(wave * 80 + r) * KP + q * 8;

  f32x4 acc[2][5];
#pragma unroll
  for (int f = 0; f < 2; f++)
#pragma unroll
    for (int j = 0; j < 5; j++) acc[f][j] = (f32x4){0.f, 0.f, 0.f, 0.f};

  // 3 in-flight register sets (prefetch distance 3); fully unrolled -> static idx
  float fv[3][4];
  uint2 ga[3], gb[3];

  auto issue = [&](int s) {
    const int set = s % 3;
    if (MODE != 1 && s < 5) {
      int kb = s * 32 + ss * 4;
#pragma unroll
      for (int j = 0; j < 4; j++) {
        int k = kb + j;
        fv[set][j] = (rok && k < FD) ? A0[(size_t)crow * FD + k] : 0.f;
      }
    } else {
      // tail reads may overrun row end by <=48B into the next row / region pad;
      // harmless: WT is zero for k past the real K.
      int kk = (s - TAIL0) * 32 + ss * 4;
      if (MODE == 2) {
        ga[set] = *(const uint2*)(amsg + (size_t)crow * HH + kk);
      } else {
        ga[set] = *(const uint2*)(amsg + (size_t)ba * HH + kk);
        gb[set] = *(const uint2*)(msgc + (size_t)rb * HH + kk);
      }
    }
  };

  auto finish = [&](int s) {
    const int set = s % 3;
    short* dst = &As[s & 3][stoff];
    if (MODE != 1 && s < 5) {
      short t[4];
#pragma unroll
      for (int j = 0; j < 4; j++) {
        union { bf16 b; short sh; } cv; cv.b = __float2bfloat16(fv[set][j]); t[j] = cv.sh;
      }
      *(uint2*)dst = *(const uint2*)t;
    } else if (MODE == 2) {
      *(uint2*)dst = ga[set];
    } else {
      unsigned wa[2] = {ga[set].x, ga[set].y};
      unsigned wb[2] = {gb[set].x, gb[set].y};
      short t[4];
#pragma unroll
      for (int p2 = 0; p2 < 2; p2++) {
        union { unsigned u; float f; } alo, ahi, blo, bhi;
        alo.u = wa[p2] << 16;         blo.u = wb[p2] << 16;
        ahi.u = wa[p2] & 0xffff0000u; bhi.u = wb[p2] & 0xffff0000u;
        union { bf16 b; short sh; } c0, c1;
        c0.b = __float2bfloat16(alo.f - blo.f);
        c1.b = __float2bfloat16(ahi.f - bhi.f);
        t[2 * p2] = c0.sh; t[2 * p2 + 1] = c1.sh;
      }
      *(uint2*)dst = *(const uint2*)t;
    }
  };

  // ---- prologue: fill pipeline (depth 3), stage step 0 ----
  issue(0); issue(1); issue(2);
  finish(0);
  asm volatile("s_waitcnt lgkmcnt(0)" ::: "memory");
  __builtin_amdgcn_s_barrier();

  // ---- main loop: one raw barrier per step, prefetched loads in flight across it ----
#pragma unroll
  for (int s = 0; s < KSTEPS; s++) {
    if (s + 3 < KSTEPS) issue(s + 3);

    {
      const short* curb = &As[s & 3][0];
      bf16x8 af[2], bfr[5];
#pragma unroll
      for (int f = 0; f < 2; f++) af[f] = *(const bf16x8*)(curb + aoff[f]);
#pragma unroll
      for (int j = 0; j < 5; j++) bfr[j] = *(const bf16x8*)(bb + (size_t)j * 16 * KP + s * 32);
#pragma unroll
      for (int j = 0; j < 5; j++)
#pragma unroll
        for (int f = 0; f < 2; f++)
          acc[f][j] = __builtin_amdgcn_mfma_f32_16x16x32_bf16(af[f], bfr[j], acc[f][j], 0, 0, 0);
    }

    if (s + 1 < KSTEPS) {
      finish(s + 1);
      asm volatile("s_waitcnt lgkmcnt(0)" ::: "memory");
      __builtin_amdgcn_s_barrier();
    }
  }

  // ---- epilogue: C/D frag col=lane&15, row=(lane>>4)*4+reg ----
#pragma unroll
  for (int j = 0; j < 5; j++) {
    int c = wave * 80 + j * 16 + r;
    if (c >= HH) continue;
    float bia = (MODE == 2) ? bias[c] : 0.f;
#pragma unroll
    for (int f = 0; f < 2; f++) {
#pragma unroll
      for (int ri = 0; ri < 4; ri++) {
        int g = gm0 + f * 16 + q * 4 + ri;
        if (g >= M) continue;
        float v = acc[f][j][ri];
        size_t o = (size_t)g * HH + c;
        if (MODE == 0) {
          if (inp_out) inp_out[o] = __float2bfloat16(v);
          float rv = fmaxf(v, 0.f);
          if (g == 0) rv = 0.f;
          msg_out[o] = __float2bfloat16(rv);
        } else if (MODE == 1) {
          float rv = fmaxf(v + __bfloat162float(inp[o]), 0.f);
          if (g == 0) rv = 0.f;
          msg_out[o] = __float2bfloat16(rv);
        } else if (MODE == 2) {
          hid_out[o] = fmaxf(v + bia, 0.f);
        } else {
          float rv = fmaxf(v, 0.f);
          if (g == 0) rv = 0.f;
          msg_out[o] = __float2bfloat16(rv);
        }
      }
    }
  }
}

// per-molecule mean over sorted mol_id (binary search, no atomics)
__global__ void readout_k(const float* __restrict__ hid, const int* __restrict__ mol_id,
                          float* __restrict__ out, int A)
{
  __shared__ int bnd[2];
  int m = blockIdx.x;
  if (threadIdx.x < 2) {
    int target = m + (int)threadIdx.x;
    int lo = 0, hi = A;
    while (lo < hi) { int mid = (lo + hi) >> 1; if (mol_id[mid] < target) lo = mid + 1; else hi = mid; }
    bnd[threadIdx.x] = lo;
  }
  __syncthreads();
  int s = bnd[0], e = bnd[1];
  int h = threadIdx.x;
  if (h >= HH) return;
  float acc = 0.f;
  for (int a = s; a < e; a++) acc += hid[(size_t)a * HH + h];
  int cnt = e - s; if (cnt < 1) cnt = 1;
  out[(size_t)m * HH + h] = acc / (float)cnt;
}

extern "C" void kernel_launch(void* const* d_in, const int* in_sizes, int n_in,
                              void* d_out, int out_size, void* d_ws, size_t ws_size,
                              hipStream_t stream)
{
  const float* f_atoms[2] = {(const float*)d_in[0], (const float*)d_in[2]};
  const float* f_bonds[2] = {(const float*)d_in[1], (const float*)d_in[3]};
  const float* W_i[2]     = {(const float*)d_in[4], (const float*)d_in[5]};
  const float* W_h[2]     = {(const float*)d_in[6], (const float*)d_in[7]};
  const float* W_o[2]     = {(const float*)d_in[8], (const float*)d_in[10]};
  const float* b_o[2]     = {(const float*)d_in[9], (const float*)d_in[11]};
  const int* a2b[2]    = {(const int*)d_in[12], (const int*)d_in[16]};
  const int* b2a[2]    = {(const int*)d_in[13], (const int*)d_in[17]};
  const int* b2revb[2] = {(const int*)d_in[14], (const int*)d_in[18]};
  const int* mol_id[2] = {(const int*)d_in[15], (const int*)d_in[19]};
  const int A = in_sizes[0] / AFD;   // 100001
  const int B = in_sizes[1] / BFD;   // 200001

  // ws: M0 bf16[B,H] | M1 bf16[B,H] / hid f32[A,H] | amsg bf16[A,H]
  //     | inp bf16[B,H] (if space) | WTI,WTH,WTO,WTC x2 passes
  auto al = [](size_t x){ return (x + 255) & ~(size_t)255; };
  size_t r0 = al((size_t)B * HH * sizeof(bf16));
  size_t r1sz = (size_t)B * HH * sizeof(bf16);
  size_t hsz  = (size_t)A * HH * sizeof(float);
  size_t r1 = al(r1sz > hsz ? r1sz : hsz);
  size_t amsz = al((size_t)A * HH * sizeof(bf16));
  size_t inpsz = al((size_t)B * HH * sizeof(bf16));
  size_t wti = al(320 * 160 * sizeof(bf16));
  size_t wth = al(320 * 320 * sizeof(bf16));
  size_t wto = al(320 * 480 * sizeof(bf16));
  size_t wtc = al(320 * 480 * sizeof(bf16));
  size_t wtsum = 2 * (wti + wth + wto + wtc);
  size_t base = r0 + r1 + amsz + wtsum;
  if (ws_size < base) return;                    // clean diagnostic fail
  const bool big = ws_size >= base + inpsz;      // inp-materialization path?

  char* ws = (char*)d_ws;
  bf16*  M0  = (bf16*)ws;
  bf16*  M1  = (bf16*)(ws + r0);
  float* hid = (float*)(ws + r0);
  bf16*  amsg = (bf16*)(ws + r0 + r1);
  size_t off = r0 + r1 + amsz;
  bf16* inp = nullptr;
  if (big) { inp = (bf16*)(ws + off); off += inpsz; }
  bf16 *WTI[2], *WTH[2], *WTO[2], *WTC[2];
  for (int p = 0; p < 2; p++) {
    WTI[p] = (bf16*)(ws + off); off += wti;
    WTH[p] = (bf16*)(ws + off); off += wth;
    WTO[p] = (bf16*)(ws + off); off += wto;
    WTC[p] = (bf16*)(ws + off); off += wtc;
  }

  dim3 blk(256);
  dim3 gB((B + 31) / 32);
  dim3 gA((A + 31) / 32);
  dim3 gG((A * 75 + 255) / 256);

  for (int p = 0; p < 2; p++) {
    build_wt<<<(320*160 + 255)/256, blk, 0, stream>>>(W_i[p], nullptr, BFD, -1, 160, WTI[p]);
    build_wt<<<(320*320 + 255)/256, blk, 0, stream>>>(nullptr, W_h[p], 0, 0, 320, WTH[p]);
    build_wt<<<(320*480 + 255)/256, blk, 0, stream>>>(W_o[p], W_o[p] + (size_t)AFD * HH,
                                                      AFD, 160, 480, WTO[p]);
    if (!big)
      build_wt<<<(320*480 + 255)/256, blk, 0, stream>>>(W_i[p], W_h[p], BFD, 160, 480, WTC[p]);
  }

  for (int p = 0; p < 2; p++) {
    float* out_p = (float*)d_out + (size_t)p * NMOLS * HH;
    if (big) {
      // inp = f_bonds@Wi (bf16); M0 = relu(inp), row0=0
      gemm32<0><<<gB, blk, 0, stream>>>(f_bonds[p], WTI[p], nullptr, nullptr, nullptr,
                                        nullptr, nullptr, nullptr, inp, M0, nullptr, B);
      // iter 1: M1 = relu(inp + (amsg[b2a]-M0[b2revb])@Wh), row0=0
      gather6_k<<<gG, blk, 0, stream>>>(M0, a2b[p], amsg, A);
      gemm32<1><<<gB, blk, 0, stream>>>(nullptr, WTH[p], b2a[p], b2revb[p], amsg, M0,
                                        inp, nullptr, nullptr, M1, nullptr, B);
      // iter 2
      gather6_k<<<gG, blk, 0, stream>>>(M1, a2b[p], amsg, A);
      gemm32<1><<<gB, blk, 0, stream>>>(nullptr, WTH[p], b2a[p], b2revb[p], amsg, M1,
                                        inp, nullptr, nullptr, M0, nullptr, B);
    } else {
      // fallback (15-step fused): identical to round-6 semantics
      gemm32<0><<<gB, blk, 0, stream>>>(f_bonds[p], WTI[p], nullptr, nullptr, nullptr,
                                        nullptr, nullptr, nullptr, nullptr, M0, nullptr, B);
      gather6_k<<<gG, blk, 0, stream>>>(M0, a2b[p], amsg, A);
      gemm32<3><<<gB, blk, 0, stream>>>(f_bonds[p], WTC[p], b2a[p], b2revb[p], amsg, M0,
                                        nullptr, nullptr, nullptr, M1, nullptr, B);
      gather6_k<<<gG, blk, 0, stream>>>(M1, a2b[p], amsg, A);
      gemm32<3><<<gB, blk, 0, stream>>>(f_bonds[p], WTC[p], b2a[p], b2revb[p], amsg, M1,
                                        nullptr, nullptr, nullptr, M0, nullptr, B);
    }
    // output layer: hid = relu([f_atoms | gather6(M0)]@Wo + b)
    gather6_k<<<gG, blk, 0, stream>>>(M0, a2b[p], amsg, A);
    gemm32<2><<<gA, blk, 0, stream>>>(f_atoms[p], WTO[p], nullptr, nullptr, amsg,
                                      nullptr, nullptr, b_o[p], nullptr, nullptr, hid, A);
    // per-molecule mean readout
    readout_k<<<NMOLS, 320, 0, stream>>>(hid, mol_id[p], out_p, A);
  }
}